// Round 5
// baseline (684.734 us; speedup 1.0000x reference)
//
#include <hip/hip_runtime.h>
#include <hip/hip_bf16.h>

#define BATCH 8192
#define DIM   2048

typedef __attribute__((ext_vector_type(8))) short  bf16x8;
typedef __attribute__((ext_vector_type(4))) float  f32x4;

__device__ __forceinline__ unsigned short f2bf(float f) {
    __hip_bfloat16 h = __float2bfloat16(f);
    return *reinterpret_cast<unsigned short*>(&h);
}

// jax.nn.gelu default approximate=True (tanh form)
__device__ __forceinline__ float gelu_f(float x) {
    const float c0 = 0.7978845608028654f;
    float x3 = x * x * x;
    float t  = tanhf(c0 * (x + 0.044715f * x3));
    return 0.5f * x * (1.0f + t);
}

__device__ __forceinline__ void gload_lds16(const void* g, void* lds) {
    __builtin_amdgcn_global_load_lds(
        (const __attribute__((address_space(1))) unsigned int*)g,
        (__attribute__((address_space(3))) unsigned int*)lds,
        16, 0, 0);
}

// ---------------- routing ----------------
__global__ void minmax_k(const float* __restrict__ u, float* __restrict__ mm,
                         int* __restrict__ flags, int n) {
    __shared__ float smn[1024], smx[1024];
    int t = threadIdx.x;
    if (t < 2) flags[t] = 0;          // zero level-flags before route_k (stream-ordered)
    const float4* p = reinterpret_cast<const float4*>(u);
    float4 a = p[2 * t], b = p[2 * t + 1];
    float mn = fminf(fminf(fminf(a.x, a.y), fminf(a.z, a.w)),
                     fminf(fminf(b.x, b.y), fminf(b.z, b.w)));
    float mx = fmaxf(fmaxf(fmaxf(a.x, a.y), fmaxf(a.z, a.w)),
                     fmaxf(fmaxf(b.x, b.y), fmaxf(b.z, b.w)));
    smn[t] = mn; smx[t] = mx;
    __syncthreads();
    for (int s = 512; s > 0; s >>= 1) {
        if (t < s) {
            smn[t] = fminf(smn[t], smn[t + s]);
            smx[t] = fmaxf(smx[t], smx[t + s]);
        }
        __syncthreads();
    }
    if (t == 0) { mm[0] = smn[0]; mm[1] = smx[0]; }
}

// Router weights staged in LDS (fixes the 165us serial-s_load pathology seen in r2).
__global__ void route_k(const float* __restrict__ unc, const float* __restrict__ mm,
                        const float* __restrict__ rw1, const float* __restrict__ rb1,
                        const float* __restrict__ rw2, const float* __restrict__ rb2,
                        const float* __restrict__ rw3, const float* __restrict__ rb3,
                        int* __restrict__ routing, float* __restrict__ mask_out,
                        int* __restrict__ flags, int n) {
    __shared__ float s_w1[32], s_b1[32], s_w2[512], s_b2[16], s_w3[48], s_b3[3];
    const int t = threadIdx.x;
    if (t < 32) { s_w1[t] = rw1[t]; s_b1[t] = rb1[t]; }
#pragma unroll
    for (int i2 = 0; i2 < 2; ++i2) s_w2[i2 * 256 + t] = rw2[i2 * 256 + t];
    if (t < 16) s_b2[t] = rb2[t];
    if (t < 48) s_w3[t] = rw3[t];
    if (t < 3)  s_b3[t] = rb3[t];
    __syncthreads();

    int i = blockIdx.x * 256 + t;
    float u = (unc[i] - mm[0]) / (mm[1] - mm[0] + 1e-8f);
    float h1[32];
#pragma unroll
    for (int j = 0; j < 32; ++j) h1[j] = fmaxf(u * s_w1[j] + s_b1[j], 0.0f);
    float h2[16];
#pragma unroll
    for (int j = 0; j < 16; ++j) {
        float s = s_b2[j];
#pragma unroll
        for (int k = 0; k < 32; ++k) s += h1[k] * s_w2[k * 16 + j];
        h2[j] = fmaxf(s, 0.0f);
    }
    float lg[3];
#pragma unroll
    for (int j = 0; j < 3; ++j) {
        float s = s_b3[j];
#pragma unroll
        for (int k = 0; k < 16; ++k) s += h2[k] * s_w3[k * 3 + j];
        lg[j] = s;
    }
    // argmax(softmax) == argmax(logits); strict '>' = first-index ties (jnp.argmax)
    int idx = 0; float best = lg[0];
    if (lg[1] > best) { best = lg[1]; idx = 1; }
    if (lg[2] > best) { best = lg[2]; idx = 2; }
    routing[i] = idx;
    mask_out[i] = (float)idx;

    // per-level presence flags (for skipping whole layers)
    unsigned long long b1 = __ballot(idx >= 1);
    unsigned long long b2 = __ballot(idx >= 2);
    if ((t & 63) == 0) {
        if (b1) atomicOr(&flags[0], 1);
        if (b2) atomicOr(&flags[1], 1);
    }
}

// ---------------- conversions ----------------
__global__ void convx_k(const float* __restrict__ in, unsigned short* __restrict__ out, int n8) {
    int i = blockIdx.x * 256 + threadIdx.x;
    if (i >= n8) return;
    const float4* p = reinterpret_cast<const float4*>(in) + (size_t)2 * i;
    float4 a = p[0], b = p[1];
    bf16x8 o;
    o[0] = (short)f2bf(a.x); o[1] = (short)f2bf(a.y);
    o[2] = (short)f2bf(a.z); o[3] = (short)f2bf(a.w);
    o[4] = (short)f2bf(b.x); o[5] = (short)f2bf(b.y);
    o[6] = (short)f2bf(b.z); o[7] = (short)f2bf(b.w);
    *(reinterpret_cast<bf16x8*>(out) + i) = o;
}

// W [K][N] f32 -> Wt [N][K] bf16 (transposed), LDS-tiled; skippable via level flag
__global__ void convw_k(const float* __restrict__ W, unsigned short* __restrict__ Wt,
                        const int* __restrict__ flags, int need_lvl) {
    if (need_lvl > 0 && flags[need_lvl - 1] == 0) return;
    __shared__ float t[32][33];
    int n0 = blockIdx.x * 32, k0 = blockIdx.y * 32;
    int tx = threadIdx.x, ty = threadIdx.y;   // 32 x 8
#pragma unroll
    for (int r = 0; r < 4; ++r)
        t[ty + 8 * r][tx] = W[(size_t)(k0 + ty + 8 * r) * DIM + n0 + tx];
    __syncthreads();
#pragma unroll
    for (int r = 0; r < 4; ++r)
        Wt[(size_t)(n0 + ty + 8 * r) * DIM + k0 + tx] = f2bf(t[tx][ty + 8 * r]);
}

// ---------------- GEMM + GELU + routed write ----------------
// Ring-2 double-buffered LDS; raw s_barrier + trailing vmcnt(0) (no per-step
// full drain: the wait targets loads issued one full iteration earlier).
__launch_bounds__(256)
__global__ void gemm_k(const unsigned short* __restrict__ A,
                       const unsigned short* __restrict__ Bt,
                       unsigned short* __restrict__ Ob,   // [M][N] bf16 scratch out
                       const float* __restrict__ bias,    // [N]
                       const int* __restrict__ routing,
                       float* __restrict__ Of,            // [M][N] f32 final out
                       int match, int store_ob, int need_lvl) {
    constexpr int N = DIM, K = DIM;
    constexpr int NT = K / 32;
    // 32 KB: two 16KB buffers {A 8KB | B 8KB}; epilogue reuses as lsC+lsF
    __shared__ short smem[16384];
    __shared__ int s_need;

    const int tid  = threadIdx.x;
    const int wg   = blockIdx.x;
    const int bm   = wg >> 4;             // 64 M-tiles
    const int bn   = wg & 15;             // 16 N-tiles
    const int m0   = bm * 128, n0 = bn * 128;

    // skip whole block if no row in this M-tile needs this layer
    if (need_lvl > 0) {
        if (tid == 0) s_need = 0;
        __syncthreads();
        if (tid < 128 && routing[m0 + tid] >= need_lvl) atomicOr(&s_need, 1);
        __syncthreads();
        if (s_need == 0) return;
    }

    const int wave = tid >> 6, lane = tid & 63;
    const int wr   = wave >> 1, wc = wave & 1;

    const int rS = tid >> 2;
    const int cS = (tid & 3) * 8;
    const char* gA = (const char*)(A  + (size_t)(m0 + rS) * K + cS);
    const char* gB = (const char*)(Bt + (size_t)(n0 + rS) * K + cS);

    f32x4 acc[4][4];
#pragma unroll
    for (int i = 0; i < 4; ++i)
#pragma unroll
        for (int j = 0; j < 4; ++j)
            acc[i][j] = (f32x4){0.f, 0.f, 0.f, 0.f};

    const int lrow = lane & 15;
    const int kb   = (lane >> 4) * 8;
    const int offA = (wr * 64 + lrow) * 32 + kb;   // shorts, within A region
    const int offB = (wc * 64 + lrow) * 32 + kb;   // shorts, within B region

    auto STAGE = [&](int kt, int b) {
        const char* ga = gA + kt * 64;             // 32 elems * 2B per K-step
        const char* gb = gB + kt * 64;
        char* la = (char*)smem + b * 16384 + wave * 1024;
        char* lb = la + 8192;
        gload_lds16(ga,                      la);
        gload_lds16(ga + (size_t)64 * K * 2, la + 4096);
        gload_lds16(gb,                      lb);
        gload_lds16(gb + (size_t)64 * K * 2, lb + 4096);
    };

    STAGE(0, 0);
#pragma unroll 2
    for (int kt = 0; kt < NT; ++kt) {
        const int cur = kt & 1;
        // tile kt's loads were issued one iteration ago -> wait is cheap.
        asm volatile("s_waitcnt vmcnt(0)" ::: "memory");
        __builtin_amdgcn_s_barrier();              // raw barrier: no lgkm/vm auto-drain
        __builtin_amdgcn_sched_barrier(0);

        const short* base = smem + cur * 8192;     // buffer base (shorts)
        bf16x8 af[4], bfr[4];
#pragma unroll
        for (int i = 0; i < 4; ++i) af[i]  = *(const bf16x8*)(base + offA + i * 16 * 32);
#pragma unroll
        for (int j = 0; j < 4; ++j) bfr[j] = *(const bf16x8*)(base + 4096 + offB + j * 16 * 32);

        if (kt + 1 < NT) STAGE(kt + 1, cur ^ 1);   // prefetch into other buffer

#pragma unroll
        for (int i = 0; i < 4; ++i)
#pragma unroll
            for (int j = 0; j < 4; ++j)
                acc[i][j] = __builtin_amdgcn_mfma_f32_16x16x32_bf16(af[i], bfr[j], acc[i][j], 0, 0, 0);
    }
    __syncthreads();   // full drain: all waves done with smem before epilogue reuse

    // ---- epilogue: C col = lane&15, row = (lane>>4)*4 + r ----
    const int crow0 = (lane >> 4) * 4;
    float bcol[4];
#pragma unroll
    for (int jb = 0; jb < 4; ++jb) bcol[jb] = bias[n0 + wc * 64 + jb * 16 + lrow];

    constexpr int CPAD = 132;
    short* lsC = smem;                          // [32][132] shorts = 8448 B
    float* lsF = (float*)((char*)smem + 8448);  // [32][132] floats = 16896 B

#pragma unroll
    for (int i = 0; i < 4; ++i) {
        float v[4][4];
#pragma unroll
        for (int jb = 0; jb < 4; ++jb)
#pragma unroll
            for (int r = 0; r < 4; ++r)
                v[jb][r] = gelu_f(acc[i][jb][r] + bcol[jb]);

        // stage the 32x128 chunk in LDS (both precisions)
#pragma unroll
        for (int r = 0; r < 4; ++r) {
            int rl = wr * 16 + crow0 + r;
#pragma unroll
            for (int jb = 0; jb < 4; ++jb) {
                int cc = wc * 64 + jb * 16 + lrow;
                lsF[rl * CPAD + cc] = v[jb][r];
                if (store_ob) lsC[rl * CPAD + cc] = f2bf(v[jb][r]);
            }
        }
        __syncthreads();

        if (store_ob) {
            // bf16 copy-out: 16 lanes x 16B = 256B contiguous per row
#pragma unroll
            for (int p = 0; p < 2; ++p) {
                int t  = p * 256 + tid;
                int rl = t >> 4;             // 0..31
                int c8 = (t & 15) * 8;       // col in shorts
                int grow = m0 + (rl >> 4) * 64 + i * 16 + (rl & 15);
                *(bf16x8*)(Ob + (size_t)grow * N + n0 + c8) =
                    *(const bf16x8*)(lsC + rl * CPAD + c8);
            }
        }
        // routed f32 copy-out: 32 lanes x 16B = 512B contiguous per row
#pragma unroll
        for (int p = 0; p < 4; ++p) {
            int t2 = p * 256 + tid;          // 0..1023
            int rl = t2 >> 5;                // 0..31
            int c4 = (t2 & 31) * 4;          // float col
            int grow = m0 + (rl >> 4) * 64 + i * 16 + (rl & 15);
            if (routing[grow] == match)
                *(float4*)(Of + (size_t)grow * N + n0 + c4) =
                    *(const float4*)(lsF + rl * CPAD + c4);
        }
        __syncthreads();
    }
}

extern "C" void kernel_launch(void* const* d_in, const int* in_sizes, int n_in,
                              void* d_out, int out_size, void* d_ws, size_t ws_size,
                              hipStream_t stream) {
    const float* x   = (const float*)d_in[0];
    const float* unc = (const float*)d_in[1];
    const float* Ws  = (const float*)d_in[2];
    const float* bs  = (const float*)d_in[3];
    const float* rw1 = (const float*)d_in[4];
    const float* rb1 = (const float*)d_in[5];
    const float* rw2 = (const float*)d_in[6];
    const float* rb2 = (const float*)d_in[7];
    const float* rw3 = (const float*)d_in[8];
    const float* rb3 = (const float*)d_in[9];
    float* out  = (float*)d_out;
    float* mask = out + (size_t)BATCH * DIM;

    // ws layout: Wb (8MB) | hb0 (32MB) | hb1 (32MB) | routing (32KB) | mm | flags
    char* ws = (char*)d_ws;
    unsigned short* Wb  = (unsigned short*)ws;
    unsigned short* hb0 = (unsigned short*)(ws + (size_t)8  * 1024 * 1024);
    unsigned short* hb1 = (unsigned short*)(ws + (size_t)40 * 1024 * 1024);
    int*   routing = (int*)  (ws + (size_t)72 * 1024 * 1024);
    float* mm      = (float*)(ws + (size_t)72 * 1024 * 1024 + 64 * 1024);
    int*   flags   = (int*)  (ws + (size_t)72 * 1024 * 1024 + 64 * 1024 + 16);

    minmax_k<<<1, 1024, 0, stream>>>(unc, mm, flags, BATCH);
    route_k<<<BATCH / 256, 256, 0, stream>>>(unc, mm, rw1, rb1, rw2, rb2, rw3, rb3,
                                             routing, mask, flags, BATCH);
    convx_k<<<(BATCH * DIM / 8 + 255) / 256, 256, 0, stream>>>(x, hb0, BATCH * DIM / 8);

    // chain: hb0(x) -W0-> hb1(lvl0) -W1-> hb0(lvl1) -W2-> hb1 -W3-> (lvl2, no Ob)
    const unsigned short* ins[4]  = {hb0, hb1, hb0, hb1};
    unsigned short*       outs[4] = {hb1, hb0, hb1, hb0};
    const int matches[4]   = {0, 1, -1, 2};
    const int store_ob[4]  = {1, 1, 1, 0};
    const int need_lvl[4]  = {0, 1, 2, 2};
    for (int l = 0; l < 4; ++l) {
        convw_k<<<dim3(64, 64), dim3(32, 8), 0, stream>>>(Ws + (size_t)l * DIM * DIM, Wb,
                                                          flags, need_lvl[l]);
        gemm_k<<<1024, 256, 0, stream>>>(ins[l], Wb, outs[l], bs + (size_t)l * DIM,
                                         routing, out, matches[l], store_ob[l], need_lvl[l]);
    }
}

// Round 6
// 525.659 us; speedup vs baseline: 1.3026x; 1.3026x over previous
//
#include <hip/hip_runtime.h>
#include <hip/hip_bf16.h>

#define BATCH 8192
#define DIM   2048

typedef __attribute__((ext_vector_type(8))) short  bf16x8;
typedef __attribute__((ext_vector_type(4))) float  f32x4;

__device__ __forceinline__ unsigned short f2bf(float f) {
    __hip_bfloat16 h = __float2bfloat16(f);
    return *reinterpret_cast<unsigned short*>(&h);
}

// jax.nn.gelu default approximate=True (tanh form)
__device__ __forceinline__ float gelu_f(float x) {
    const float c0 = 0.7978845608028654f;
    float x3 = x * x * x;
    float t  = tanhf(c0 * (x + 0.044715f * x3));
    return 0.5f * x * (1.0f + t);
}

__device__ __forceinline__ void gload_lds16(const void* g, void* lds) {
    __builtin_amdgcn_global_load_lds(
        (const __attribute__((address_space(1))) unsigned int*)g,
        (__attribute__((address_space(3))) unsigned int*)lds,
        16, 0, 0);
}

// ---------------- routing ----------------
__global__ void minmax_k(const float* __restrict__ u, float* __restrict__ mm,
                         int* __restrict__ flags, int n) {
    __shared__ float smn[1024], smx[1024];
    int t = threadIdx.x;
    if (t < 2) flags[t] = 0;
    const float4* p = reinterpret_cast<const float4*>(u);
    float4 a = p[2 * t], b = p[2 * t + 1];
    float mn = fminf(fminf(fminf(a.x, a.y), fminf(a.z, a.w)),
                     fminf(fminf(b.x, b.y), fminf(b.z, b.w)));
    float mx = fmaxf(fmaxf(fmaxf(a.x, a.y), fmaxf(a.z, a.w)),
                     fmaxf(fmaxf(b.x, b.y), fmaxf(b.z, b.w)));
    smn[t] = mn; smx[t] = mx;
    __syncthreads();
    for (int s = 512; s > 0; s >>= 1) {
        if (t < s) {
            smn[t] = fminf(smn[t], smn[t + s]);
            smx[t] = fmaxf(smx[t], smx[t + s]);
        }
        __syncthreads();
    }
    if (t == 0) { mm[0] = smn[0]; mm[1] = smx[0]; }
}

// Router weights staged in LDS (fixes the 165us serial-s_load pathology, r2).
__global__ void route_k(const float* __restrict__ unc, const float* __restrict__ mm,
                        const float* __restrict__ rw1, const float* __restrict__ rb1,
                        const float* __restrict__ rw2, const float* __restrict__ rb2,
                        const float* __restrict__ rw3, const float* __restrict__ rb3,
                        int* __restrict__ routing, float* __restrict__ mask_out,
                        int* __restrict__ flags, int n) {
    __shared__ float s_w1[32], s_b1[32], s_w2[512], s_b2[16], s_w3[48], s_b3[3];
    const int t = threadIdx.x;
    if (t < 32) { s_w1[t] = rw1[t]; s_b1[t] = rb1[t]; }
#pragma unroll
    for (int i2 = 0; i2 < 2; ++i2) s_w2[i2 * 256 + t] = rw2[i2 * 256 + t];
    if (t < 16) s_b2[t] = rb2[t];
    if (t < 48) s_w3[t] = rw3[t];
    if (t < 3)  s_b3[t] = rb3[t];
    __syncthreads();

    int i = blockIdx.x * 256 + t;
    float u = (unc[i] - mm[0]) / (mm[1] - mm[0] + 1e-8f);
    float h1[32];
#pragma unroll
    for (int j = 0; j < 32; ++j) h1[j] = fmaxf(u * s_w1[j] + s_b1[j], 0.0f);
    float h2[16];
#pragma unroll
    for (int j = 0; j < 16; ++j) {
        float s = s_b2[j];
#pragma unroll
        for (int k = 0; k < 32; ++k) s += h1[k] * s_w2[k * 16 + j];
        h2[j] = fmaxf(s, 0.0f);
    }
    float lg[3];
#pragma unroll
    for (int j = 0; j < 3; ++j) {
        float s = s_b3[j];
#pragma unroll
        for (int k = 0; k < 16; ++k) s += h2[k] * s_w3[k * 3 + j];
        lg[j] = s;
    }
    // argmax(softmax) == argmax(logits); strict '>' = first-index ties (jnp.argmax)
    int idx = 0; float best = lg[0];
    if (lg[1] > best) { best = lg[1]; idx = 1; }
    if (lg[2] > best) { best = lg[2]; idx = 2; }
    routing[i] = idx;
    mask_out[i] = (float)idx;

    unsigned long long b1 = __ballot(idx >= 1);
    unsigned long long b2 = __ballot(idx >= 2);
    if ((t & 63) == 0) {
        if (b1) atomicOr(&flags[0], 1);
        if (b2) atomicOr(&flags[1], 1);
    }
}

// ---------------- conversions ----------------
__global__ void convx_k(const float* __restrict__ in, unsigned short* __restrict__ out, int n8) {
    int i = blockIdx.x * 256 + threadIdx.x;
    if (i >= n8) return;
    const float4* p = reinterpret_cast<const float4*>(in) + (size_t)2 * i;
    float4 a = p[0], b = p[1];
    bf16x8 o;
    o[0] = (short)f2bf(a.x); o[1] = (short)f2bf(a.y);
    o[2] = (short)f2bf(a.z); o[3] = (short)f2bf(a.w);
    o[4] = (short)f2bf(b.x); o[5] = (short)f2bf(b.y);
    o[6] = (short)f2bf(b.z); o[7] = (short)f2bf(b.w);
    *(reinterpret_cast<bf16x8*>(out) + i) = o;
}

// W [K][N] f32 -> Wt [N][K] bf16 (transposed), LDS-tiled; skippable via level flag
__global__ void convw_k(const float* __restrict__ W, unsigned short* __restrict__ Wt,
                        const int* __restrict__ flags, int need_lvl) {
    if (need_lvl > 0 && flags[need_lvl - 1] == 0) return;
    __shared__ float t[32][33];
    int n0 = blockIdx.x * 32, k0 = blockIdx.y * 32;
    int tx = threadIdx.x, ty = threadIdx.y;   // 32 x 8
#pragma unroll
    for (int r = 0; r < 4; ++r)
        t[ty + 8 * r][tx] = W[(size_t)(k0 + ty + 8 * r) * DIM + n0 + tx];
    __syncthreads();
#pragma unroll
    for (int r = 0; r < 4; ++r)
        Wt[(size_t)(n0 + ty + 8 * r) * DIM + k0 + tx] = f2bf(t[tx][ty + 8 * r]);
}

// ---------------- 256x256 8-phase GEMM + GELU + routed write ----------------
// C[m][n] = gelu(sum_k A[m][k] * Bt[n][k] + bias[n])
// BM=BN=256, BK=64, 512 thr = 8 waves (2M x 4N), per-wave out 128x64.
// LDS 128KiB = 2 dbuf x (A 32KB + B 32KB). 16B-chunk XOR swizzle (chunk ^= row&7)
// applied on BOTH sides: inverse-swizzled global source for global_load_lds
// (linear LDS dest) + swizzled ds_read address.
__launch_bounds__(512, 2)
__global__ void gemm_k(const unsigned short* __restrict__ A,
                       const unsigned short* __restrict__ Bt,
                       unsigned short* __restrict__ Ob,   // [M][N] bf16 scratch out
                       const float* __restrict__ bias,    // [N]
                       const int* __restrict__ routing,
                       float* __restrict__ Of,            // [M][N] f32 final out
                       int match, int store_ob, int need_lvl) {
    constexpr int N = DIM, K = DIM;
    constexpr int NT = K / 64;            // 32 K-tiles
    __shared__ char smem[131072];
    __shared__ int s_need;

    const int tid = threadIdx.x;
    // XCD-contiguous remap: 256 wgs, 8 XCDs -> XCD x owns wg [x*32, x*32+32)
    const int wg  = (blockIdx.x & 7) * 32 + (blockIdx.x >> 3);
    const int bm  = wg >> 3;              // 32 M-tiles
    const int bn  = wg & 7;               // 8 N-tiles
    const int m0  = bm * 256, n0 = bn * 256;

    // skip whole block if no row in this 256-row M-tile needs this layer
    if (need_lvl > 0) {
        if (tid == 0) s_need = 0;
        __syncthreads();
        if (tid < 256 && routing[m0 + tid] >= need_lvl) atomicOr(&s_need, 1);
        __syncthreads();
        if (s_need == 0) return;
    }

    const int wave = tid >> 6, lane = tid & 63;
    const int wm = wave >> 2, wn = wave & 3;      // 2M x 4N wave grid

    // ---- staging helpers (linear LDS dest, inverse-swizzled global src) ----
    const int sr = tid >> 3;              // base tile-row contribution 0..63
    const int sc = tid & 7;               // 16B store-chunk within 128B row
    auto STAGE_A = [&](int tt, int bb) {
#pragma unroll
        for (int s = 0; s < 4; ++s) {
            int r  = s * 64 + sr;                          // tile row 0..255
            int ce = ((sc ^ (r & 7)) << 3);                // inv-swizzled elem col
            gload_lds16(A + (size_t)(m0 + r) * K + (tt << 6) + ce,
                        smem + bb + s * 8192 + wave * 1024);
        }
    };
    auto STAGE_B = [&](int tt, int bb) {
#pragma unroll
        for (int s = 0; s < 4; ++s) {
            int r  = s * 64 + sr;
            int ce = ((sc ^ (r & 7)) << 3);
            gload_lds16(Bt + (size_t)(n0 + r) * K + (tt << 6) + ce,
                        smem + bb + 32768 + s * 8192 + wave * 1024);
        }
    };

    f32x4 acc[8][4];
#pragma unroll
    for (int i = 0; i < 8; ++i)
#pragma unroll
        for (int j = 0; j < 4; ++j)
            acc[i][j] = (f32x4){0.f, 0.f, 0.f, 0.f};

    const int lrow = lane & 15;
    // swizzled in-row byte offset for logical k-chunk (ks*4 + lane>>4):
    const int ck0 = (((lane >> 4)    ) ^ (lane & 7)) << 4;   // ks=0
    const int ck1 = (((lane >> 4) + 4) ^ (lane & 7)) << 4;   // ks=1
    const int aRow0 = wm * 16384;                 // A half base (bytes)
    const int bRow0 = 32768 + (wn >> 1) * 16384;  // B half base (bytes)
    const int bInH  = (wn & 1) * 64;              // within-half N-row base

    // prologue: stage tile 0 into buf0, full drain
    STAGE_A(0, 0);
    STAGE_B(0, 0);
    __syncthreads();

    for (int t = 0; t < NT; ++t) {
        const int bsel = (t & 1) * 65536;
        const char* buf = smem + bsel;
        const int nbuf = bsel ^ 65536;
        bf16x8 aF[4][2], bF[2][2][2];     // aF[mf][ks], bF[qn][g][ks]

        // ---- phase 0: quadrant (qm0,qn0); read A-low(8) + B-half0(4); stage A(t+1)
#pragma unroll
        for (int f = 0; f < 4; ++f) {
            int ro = aRow0 + (f * 16 + lrow) * 128;
            aF[f][0] = *(const bf16x8*)(buf + ro + ck0);
            aF[f][1] = *(const bf16x8*)(buf + ro + ck1);
        }
#pragma unroll
        for (int g = 0; g < 2; ++g) {
            int ro = bRow0 + (bInH + g * 16 + lrow) * 128;
            bF[0][g][0] = *(const bf16x8*)(buf + ro + ck0);
            bF[0][g][1] = *(const bf16x8*)(buf + ro + ck1);
        }
        if (t + 1 < NT) STAGE_A(t + 1, nbuf);
        asm volatile("s_barrier" ::: "memory");
        __builtin_amdgcn_s_setprio(1);
#pragma unroll
        for (int ks = 0; ks < 2; ++ks)
#pragma unroll
            for (int f = 0; f < 4; ++f)
#pragma unroll
                for (int g = 0; g < 2; ++g)
                    acc[f][g] = __builtin_amdgcn_mfma_f32_16x16x32_bf16(
                        aF[f][ks], bF[0][g][ks], acc[f][g], 0, 0, 0);
        __builtin_amdgcn_s_setprio(0);
        asm volatile("s_barrier" ::: "memory");

        // ---- phase 1: quadrant (0,1); read B-half1(4); stage B(t+1)
#pragma unroll
        for (int g = 0; g < 2; ++g) {
            int ro = bRow0 + (bInH + 32 + g * 16 + lrow) * 128;
            bF[1][g][0] = *(const bf16x8*)(buf + ro + ck0);
            bF[1][g][1] = *(const bf16x8*)(buf + ro + ck1);
        }
        if (t + 1 < NT) STAGE_B(t + 1, nbuf);
        asm volatile("s_barrier" ::: "memory");
        __builtin_amdgcn_s_setprio(1);
#pragma unroll
        for (int ks = 0; ks < 2; ++ks)
#pragma unroll
            for (int f = 0; f < 4; ++f)
#pragma unroll
                for (int g = 0; g < 2; ++g)
                    acc[f][2 + g] = __builtin_amdgcn_mfma_f32_16x16x32_bf16(
                        aF[f][ks], bF[1][g][ks], acc[f][2 + g], 0, 0, 0);
        __builtin_amdgcn_s_setprio(0);
        asm volatile("s_barrier" ::: "memory");

        // ---- phase 2: quadrant (1,1); read A-high(8), reuse B-half1
#pragma unroll
        for (int f = 0; f < 4; ++f) {
            int ro = aRow0 + (64 + f * 16 + lrow) * 128;
            aF[f][0] = *(const bf16x8*)(buf + ro + ck0);
            aF[f][1] = *(const bf16x8*)(buf + ro + ck1);
        }
        asm volatile("s_barrier" ::: "memory");
        __builtin_amdgcn_s_setprio(1);
#pragma unroll
        for (int ks = 0; ks < 2; ++ks)
#pragma unroll
            for (int f = 0; f < 4; ++f)
#pragma unroll
                for (int g = 0; g < 2; ++g)
                    acc[4 + f][2 + g] = __builtin_amdgcn_mfma_f32_16x16x32_bf16(
                        aF[f][ks], bF[1][g][ks], acc[4 + f][2 + g], 0, 0, 0);
        __builtin_amdgcn_s_setprio(0);
        asm volatile("s_barrier" ::: "memory");

        // ---- phase 3: quadrant (1,0); reuse A-high + B-half0; tile-boundary drain
        asm volatile("s_barrier" ::: "memory");
        __builtin_amdgcn_s_setprio(1);
#pragma unroll
        for (int ks = 0; ks < 2; ++ks)
#pragma unroll
            for (int f = 0; f < 4; ++f)
#pragma unroll
                for (int g = 0; g < 2; ++g)
                    acc[4 + f][g] = __builtin_amdgcn_mfma_f32_16x16x32_bf16(
                        aF[f][ks], bF[0][g][ks], acc[4 + f][g], 0, 0, 0);
        __builtin_amdgcn_s_setprio(0);
        asm volatile("s_waitcnt vmcnt(0)" ::: "memory");   // t+1's stages landed
        asm volatile("s_barrier" ::: "memory");
    }

    // ---- epilogue: C col = lane&15, row = (lane>>4)*4 + rr; direct stores ----
    const int r0 = m0 + wm * 128;
    const int c0 = n0 + wn * 64;
    float bcol[4];
#pragma unroll
    for (int nf = 0; nf < 4; ++nf) bcol[nf] = bias[c0 + nf * 16 + lrow];
    const int rsub = (lane >> 4) * 4;

#pragma unroll
    for (int mf = 0; mf < 8; ++mf) {
#pragma unroll
        for (int rr = 0; rr < 4; ++rr) {
            int row = r0 + mf * 16 + rsub + rr;
            int rt  = routing[row];
            size_t base = (size_t)row * N + c0 + lrow;
#pragma unroll
            for (int nf = 0; nf < 4; ++nf) {
                float v = gelu_f(acc[mf][nf][rr] + bcol[nf]);
                if (store_ob)    Ob[base + nf * 16] = f2bf(v);
                if (rt == match) Of[base + nf * 16] = v;
            }
        }
    }
}

extern "C" void kernel_launch(void* const* d_in, const int* in_sizes, int n_in,
                              void* d_out, int out_size, void* d_ws, size_t ws_size,
                              hipStream_t stream) {
    const float* x   = (const float*)d_in[0];
    const float* unc = (const float*)d_in[1];
    const float* Ws  = (const float*)d_in[2];
    const float* bs  = (const float*)d_in[3];
    const float* rw1 = (const float*)d_in[4];
    const float* rb1 = (const float*)d_in[5];
    const float* rw2 = (const float*)d_in[6];
    const float* rb2 = (const float*)d_in[7];
    const float* rw3 = (const float*)d_in[8];
    const float* rb3 = (const float*)d_in[9];
    float* out  = (float*)d_out;
    float* mask = out + (size_t)BATCH * DIM;

    // ws layout: Wb (8MB) | hb0 (32MB) | hb1 (32MB) | routing (32KB) | mm | flags
    char* ws = (char*)d_ws;
    unsigned short* Wb  = (unsigned short*)ws;
    unsigned short* hb0 = (unsigned short*)(ws + (size_t)8  * 1024 * 1024);
    unsigned short* hb1 = (unsigned short*)(ws + (size_t)40 * 1024 * 1024);
    int*   routing = (int*)  (ws + (size_t)72 * 1024 * 1024);
    float* mm      = (float*)(ws + (size_t)72 * 1024 * 1024 + 64 * 1024);
    int*   flags   = (int*)  (ws + (size_t)72 * 1024 * 1024 + 64 * 1024 + 16);

    minmax_k<<<1, 1024, 0, stream>>>(unc, mm, flags, BATCH);
    route_k<<<BATCH / 256, 256, 0, stream>>>(unc, mm, rw1, rb1, rw2, rb2, rw3, rb3,
                                             routing, mask, flags, BATCH);
    convx_k<<<(BATCH * DIM / 8 + 255) / 256, 256, 0, stream>>>(x, hb0, BATCH * DIM / 8);

    // chain: hb0(x) -W0-> hb1(lvl0) -W1-> hb0(lvl1) -W2-> hb1 -W3-> (lvl2, no Ob)
    const unsigned short* ins[4]  = {hb0, hb1, hb0, hb1};
    unsigned short*       outs[4] = {hb1, hb0, hb1, hb0};
    const int matches[4]   = {0, 1, -1, 2};
    const int store_ob[4]  = {1, 1, 1, 0};
    const int need_lvl[4]  = {0, 1, 2, 2};
    for (int l = 0; l < 4; ++l) {
        convw_k<<<dim3(64, 64), dim3(32, 8), 0, stream>>>(Ws + (size_t)l * DIM * DIM, Wb,
                                                          flags, need_lvl[l]);
        gemm_k<<<256, 512, 0, stream>>>(ins[l], Wb, outs[l], bs + (size_t)l * DIM,
                                        routing, out, matches[l], store_ob[l], need_lvl[l]);
    }
}

// Round 8
// 496.740 us; speedup vs baseline: 1.3785x; 1.0582x over previous
//
#include <hip/hip_runtime.h>
#include <hip/hip_bf16.h>

#define BATCH 8192
#define DIM   2048

typedef __attribute__((ext_vector_type(8))) short  bf16x8;
typedef __attribute__((ext_vector_type(4))) float  f32x4;

__device__ __forceinline__ unsigned short f2bf(float f) {
    __hip_bfloat16 h = __float2bfloat16(f);
    return *reinterpret_cast<unsigned short*>(&h);
}

// jax.nn.gelu default approximate=True (tanh form)
__device__ __forceinline__ float gelu_f(float x) {
    const float c0 = 0.7978845608028654f;
    float x3 = x * x * x;
    float t  = tanhf(c0 * (x + 0.044715f * x3));
    return 0.5f * x * (1.0f + t);
}

__device__ __forceinline__ void gload_lds16(const void* g, void* lds) {
    __builtin_amdgcn_global_load_lds(
        (const __attribute__((address_space(1))) unsigned int*)g,
        (__attribute__((address_space(3))) unsigned int*)lds,
        16, 0, 0);
}

// ---------------- routing ----------------
__global__ void minmax_k(const float* __restrict__ u, float* __restrict__ mm,
                         int* __restrict__ flags, int n) {
    __shared__ float smn[1024], smx[1024];
    int t = threadIdx.x;
    if (t < 2) flags[t] = 0;
    const float4* p = reinterpret_cast<const float4*>(u);
    float4 a = p[2 * t], b = p[2 * t + 1];
    float mn = fminf(fminf(fminf(a.x, a.y), fminf(a.z, a.w)),
                     fminf(fminf(b.x, b.y), fminf(b.z, b.w)));
    float mx = fmaxf(fmaxf(fmaxf(a.x, a.y), fmaxf(a.z, a.w)),
                     fmaxf(fmaxf(b.x, b.y), fmaxf(b.z, b.w)));
    smn[t] = mn; smx[t] = mx;
    __syncthreads();
    for (int s = 512; s > 0; s >>= 1) {
        if (t < s) {
            smn[t] = fminf(smn[t], smn[t + s]);
            smx[t] = fmaxf(smx[t], smx[t + s]);
        }
        __syncthreads();
    }
    if (t == 0) { mm[0] = smn[0]; mm[1] = smx[0]; }
}

// Router weights staged in LDS (fixes the 165us serial-s_load pathology, r2).
__global__ void route_k(const float* __restrict__ unc, const float* __restrict__ mm,
                        const float* __restrict__ rw1, const float* __restrict__ rb1,
                        const float* __restrict__ rw2, const float* __restrict__ rb2,
                        const float* __restrict__ rw3, const float* __restrict__ rb3,
                        int* __restrict__ routing, float* __restrict__ mask_out,
                        int* __restrict__ flags, int n) {
    __shared__ float s_w1[32], s_b1[32], s_w2[512], s_b2[16], s_w3[48], s_b3[3];
    const int t = threadIdx.x;
    if (t < 32) { s_w1[t] = rw1[t]; s_b1[t] = rb1[t]; }
#pragma unroll
    for (int i2 = 0; i2 < 2; ++i2) s_w2[i2 * 256 + t] = rw2[i2 * 256 + t];
    if (t < 16) s_b2[t] = rb2[t];
    if (t < 48) s_w3[t] = rw3[t];
    if (t < 3)  s_b3[t] = rb3[t];
    __syncthreads();

    int i = blockIdx.x * 256 + t;
    float u = (unc[i] - mm[0]) / (mm[1] - mm[0] + 1e-8f);
    float h1[32];
#pragma unroll
    for (int j = 0; j < 32; ++j) h1[j] = fmaxf(u * s_w1[j] + s_b1[j], 0.0f);
    float h2[16];
#pragma unroll
    for (int j = 0; j < 16; ++j) {
        float s = s_b2[j];
#pragma unroll
        for (int k = 0; k < 32; ++k) s += h1[k] * s_w2[k * 16 + j];
        h2[j] = fmaxf(s, 0.0f);
    }
    float lg[3];
#pragma unroll
    for (int j = 0; j < 3; ++j) {
        float s = s_b3[j];
#pragma unroll
        for (int k = 0; k < 16; ++k) s += h2[k] * s_w3[k * 3 + j];
        lg[j] = s;
    }
    // argmax(softmax) == argmax(logits); strict '>' = first-index ties (jnp.argmax)
    int idx = 0; float best = lg[0];
    if (lg[1] > best) { best = lg[1]; idx = 1; }
    if (lg[2] > best) { best = lg[2]; idx = 2; }
    routing[i] = idx;
    mask_out[i] = (float)idx;

    unsigned long long b1 = __ballot(idx >= 1);
    unsigned long long b2 = __ballot(idx >= 2);
    if ((t & 63) == 0) {
        if (b1) atomicOr(&flags[0], 1);
        if (b2) atomicOr(&flags[1], 1);
    }
}

// ---------------- conversions ----------------
__global__ void convx_k(const float* __restrict__ in, unsigned short* __restrict__ out, int n8) {
    int i = blockIdx.x * 256 + threadIdx.x;
    if (i >= n8) return;
    const float4* p = reinterpret_cast<const float4*>(in) + (size_t)2 * i;
    float4 a = p[0], b = p[1];
    bf16x8 o;
    o[0] = (short)f2bf(a.x); o[1] = (short)f2bf(a.y);
    o[2] = (short)f2bf(a.z); o[3] = (short)f2bf(a.w);
    o[4] = (short)f2bf(b.x); o[5] = (short)f2bf(b.y);
    o[6] = (short)f2bf(b.z); o[7] = (short)f2bf(b.w);
    *(reinterpret_cast<bf16x8*>(out) + i) = o;
}

// W [K][N] f32 -> Wt [N][K] bf16 (transposed), LDS-tiled; skippable via level flag
__global__ void convw_k(const float* __restrict__ W, unsigned short* __restrict__ Wt,
                        const int* __restrict__ flags, int need_lvl) {
    if (need_lvl > 0 && flags[need_lvl - 1] == 0) return;
    __shared__ float t[32][33];
    int n0 = blockIdx.x * 32, k0 = blockIdx.y * 32;
    int tx = threadIdx.x, ty = threadIdx.y;   // 32 x 8
#pragma unroll
    for (int r = 0; r < 4; ++r)
        t[ty + 8 * r][tx] = W[(size_t)(k0 + ty + 8 * r) * DIM + n0 + tx];
    __syncthreads();
#pragma unroll
    for (int r = 0; r < 4; ++r)
        Wt[(size_t)(n0 + ty + 8 * r) * DIM + k0 + tx] = f2bf(t[tx][ty + 8 * r]);
}

// ---------------- 256x256 8-phase GEMM, counted-vmcnt pipeline (T2+T3+T4+T5) ----
// C[m][n] = gelu(sum_k A[m][k] * Bt[n][k] + bias[n])
// BM=BN=256, BK=64, 512 thr = 8 waves (2M x 4N). LDS 128KiB = 2 dbuf x (A32K|B32K),
// each tile in 2 halves per operand (A0/A1 = M-rows 0-127/128-255 of the tile,
// B0/B1 likewise). Fragment rows are strided so phase reads == staged halves:
//   A frag f (of 8): row = (f&3)*32 + wm*16 + lrow   (+128 for f>=4)
//   B frag g (of 4): row = g*64 + wn*16 + lrow
// Phases: P0 reads A-low+B-low, stages A0,B0(t+1); P1 reads B-high, stages B1(t+1);
// P2 reads A-high, stages A1(t+1); P3 pure MFMA. Counted waits (never 0 mid-loop):
// vmcnt(6) @P0 end (completes B1(t)), vmcnt(6) @P1 end (A1(t)), vmcnt(4) @P3 end
// (A0,B0(t+1)). 16B-chunk XOR swizzle (chunk ^= row&7) on BOTH sides (rule #21).
__launch_bounds__(512, 2)
__global__ void gemm_k(const unsigned short* __restrict__ A,
                       const unsigned short* __restrict__ Bt,
                       unsigned short* __restrict__ Ob,   // [M][N] bf16 scratch out
                       const float* __restrict__ bias,    // [N]
                       const int* __restrict__ routing,
                       float* __restrict__ Of,            // [M][N] f32 final out
                       int match, int store_ob, int need_lvl) {
    constexpr int N = DIM, K = DIM;
    constexpr int NT = K / 64;            // 32 K-tiles
    __shared__ char smem[131072];
    __shared__ int s_need;

    const int tid = threadIdx.x;
    // XCD-contiguous remap: 256 wgs, 8 XCDs -> XCD x owns wg [x*32, x*32+32)
    const int wg  = (blockIdx.x & 7) * 32 + (blockIdx.x >> 3);
    const int bm  = wg >> 3;              // 32 M-tiles
    const int bn  = wg & 7;               // 8 N-tiles
    const int m0  = bm * 256, n0 = bn * 256;

    if (need_lvl > 0) {
        if (tid == 0) s_need = 0;
        __syncthreads();
        if (tid < 256 && routing[m0 + tid] >= need_lvl) atomicOr(&s_need, 1);
        __syncthreads();
        if (s_need == 0) return;
    }

    const int wave = tid >> 6, lane = tid & 63;
    const int wm = wave >> 2, wn = wave & 3;      // 2M x 4N wave grid

    // ---- staging (linear LDS dest, inverse-swizzled global src) ----
    const int srow = tid >> 3;                              // 0..63
    const int sw8  = ((tid & 7) ^ (srow & 7)) << 3;         // inv-swizzled elem col
    const unsigned short* gA0 = A  + (size_t)(m0 + srow) * K + sw8;
    const unsigned short* gB0 = Bt + (size_t)(n0 + srow) * K + sw8;
    const int ldsw = wave * 1024;
    // half-tile stage: 2 x gload_lds16 (rows srow, srow+64 of the half)
    auto STAGE = [&](const unsigned short* gb, int koff, int lo) {
        gload_lds16(gb + koff,                 smem + lo + ldsw);
        gload_lds16(gb + (size_t)64 * K + koff, smem + lo + 8192 + ldsw);
    };
    const unsigned short* gA1 = gA0 + (size_t)128 * K;
    const unsigned short* gB1 = gB0 + (size_t)128 * K;

    f32x4 acc[8][4];
#pragma unroll
    for (int i = 0; i < 8; ++i)
#pragma unroll
        for (int j = 0; j < 4; ++j)
            acc[i][j] = (f32x4){0.f, 0.f, 0.f, 0.f};

    const int lrow = lane & 15;
    const int ck0 = (((lane >> 4)    ) ^ (lane & 7)) << 4;   // swizzled 16B chunk, ks=0
    const int ck1 = (((lane >> 4) + 4) ^ (lane & 7)) << 4;   // ks=1

    // prologue: stage tile 0 (order A0,B0,B1,A1), wait A0+B0, raw barrier
    STAGE(gA0, 0, 0);
    STAGE(gB0, 0, 32768);
    STAGE(gB1, 0, 49152);
    STAGE(gA1, 0, 16384);
    asm volatile("s_waitcnt vmcnt(4)" ::: "memory");
    __builtin_amdgcn_s_barrier();

    for (int t = 0; t < NT; ++t) {
        const int bsel = (t & 1) << 16;
        const char* buf = smem + bsel;
        const int nb   = bsel ^ 65536;
        const int ko   = (t + 1) << 6;    // next tile's k elem offset
        const bool pre = (t + 1 < NT);
        bf16x8 aF[4][2], bL[2][2], bH[2][2];

        // ---- P0: read A-low + B-low; stage A0,B0(t+1); vmcnt(6)
#pragma unroll
        for (int f = 0; f < 4; ++f) {
            int ro = (f * 32 + wm * 16 + lrow) * 128;
            aF[f][0] = *(const bf16x8*)(buf + ro + ck0);
            aF[f][1] = *(const bf16x8*)(buf + ro + ck1);
        }
#pragma unroll
        for (int g = 0; g < 2; ++g) {
            int ro = 32768 + (g * 64 + wn * 16 + lrow) * 128;
            bL[g][0] = *(const bf16x8*)(buf + ro + ck0);
            bL[g][1] = *(const bf16x8*)(buf + ro + ck1);
        }
        if (pre) {
            STAGE(gA0, ko, nb);
            STAGE(gB0, ko, nb + 32768);
            asm volatile("s_waitcnt vmcnt(6)" ::: "memory");
        } else {
            asm volatile("s_waitcnt vmcnt(2)" ::: "memory");
        }
        __builtin_amdgcn_s_barrier();
        __builtin_amdgcn_s_setprio(1);
#pragma unroll
        for (int ks = 0; ks < 2; ++ks)
#pragma unroll
            for (int f = 0; f < 4; ++f)
#pragma unroll
                for (int g = 0; g < 2; ++g)
                    acc[f][g] = __builtin_amdgcn_mfma_f32_16x16x32_bf16(
                        aF[f][ks], bL[g][ks], acc[f][g], 0, 0, 0);
        __builtin_amdgcn_s_setprio(0);
        __builtin_amdgcn_s_barrier();

        // ---- P1: read B-high; stage B1(t+1); vmcnt(6)
#pragma unroll
        for (int g = 0; g < 2; ++g) {
            int ro = 32768 + (128 + g * 64 + wn * 16 + lrow) * 128;
            bH[g][0] = *(const bf16x8*)(buf + ro + ck0);
            bH[g][1] = *(const bf16x8*)(buf + ro + ck1);
        }
        if (pre) {
            STAGE(gB1, ko, nb + 49152);
            asm volatile("s_waitcnt vmcnt(6)" ::: "memory");
        } else {
            asm volatile("s_waitcnt vmcnt(0)" ::: "memory");
        }
        __builtin_amdgcn_s_barrier();
        __builtin_amdgcn_s_setprio(1);
#pragma unroll
        for (int ks = 0; ks < 2; ++ks)
#pragma unroll
            for (int f = 0; f < 4; ++f)
#pragma unroll
                for (int g = 0; g < 2; ++g)
                    acc[f][2 + g] = __builtin_amdgcn_mfma_f32_16x16x32_bf16(
                        aF[f][ks], bH[g][ks], acc[f][2 + g], 0, 0, 0);
        __builtin_amdgcn_s_setprio(0);
        __builtin_amdgcn_s_barrier();

        // ---- P2: read A-high (overwrite aF); stage A1(t+1); no wait
#pragma unroll
        for (int f = 0; f < 4; ++f) {
            int ro = (128 + f * 32 + wm * 16 + lrow) * 128;
            aF[f][0] = *(const bf16x8*)(buf + ro + ck0);
            aF[f][1] = *(const bf16x8*)(buf + ro + ck1);
        }
        if (pre) STAGE(gA1, ko, nb + 16384);
        __builtin_amdgcn_s_barrier();
        __builtin_amdgcn_s_setprio(1);
#pragma unroll
        for (int ks = 0; ks < 2; ++ks)
#pragma unroll
            for (int f = 0; f < 4; ++f)
#pragma unroll
                for (int g = 0; g < 2; ++g)
                    acc[4 + f][2 + g] = __builtin_amdgcn_mfma_f32_16x16x32_bf16(
                        aF[f][ks], bH[g][ks], acc[4 + f][2 + g], 0, 0, 0);
        __builtin_amdgcn_s_setprio(0);
        __builtin_amdgcn_s_barrier();

        // ---- P3: pure MFMA; tile-boundary counted wait vmcnt(4)
        if (pre) asm volatile("s_waitcnt vmcnt(4)" ::: "memory");
        __builtin_amdgcn_s_barrier();
        __builtin_amdgcn_s_setprio(1);
#pragma unroll
        for (int ks = 0; ks < 2; ++ks)
#pragma unroll
            for (int f = 0; f < 4; ++f)
#pragma unroll
                for (int g = 0; g < 2; ++g)
                    acc[4 + f][g] = __builtin_amdgcn_mfma_f32_16x16x32_bf16(
                        aF[f][ks], bL[g][ks], acc[4 + f][g], 0, 0, 0);
        __builtin_amdgcn_s_setprio(0);
        __builtin_amdgcn_s_barrier();
    }

    // ---- epilogue: C col = lane&15, row = (lane>>4)*4 + rr; direct stores ----
    // frag->coord: row = m0 + (mf&3)*32 + (mf>>2)*128 + wm*16 + rsub + rr
    //              col = n0 + nf*64 + wn*16 + lrow
    const int c0 = n0 + wn * 16;
    float bcol[4];
#pragma unroll
    for (int nf = 0; nf < 4; ++nf) bcol[nf] = bias[c0 + nf * 64 + lrow];
    const int rsub = (lane >> 4) * 4;

#pragma unroll
    for (int mf = 0; mf < 8; ++mf) {
        const int rbase = m0 + (mf & 3) * 32 + (mf >> 2) * 128 + wm * 16 + rsub;
#pragma unroll
        for (int rr = 0; rr < 4; ++rr) {
            int row = rbase + rr;
            int rt  = routing[row];
            size_t base = (size_t)row * N + c0 + lrow;
#pragma unroll
            for (int nf = 0; nf < 4; ++nf) {
                float v = gelu_f(acc[mf][nf][rr] + bcol[nf]);
                if (store_ob)    Ob[base + nf * 64] = f2bf(v);
                if (rt == match) Of[base + nf * 64] = v;
            }
        }
    }
}

extern "C" void kernel_launch(void* const* d_in, const int* in_sizes, int n_in,
                              void* d_out, int out_size, void* d_ws, size_t ws_size,
                              hipStream_t stream) {
    const float* x   = (const float*)d_in[0];
    const float* unc = (const float*)d_in[1];
    const float* Ws  = (const float*)d_in[2];
    const float* bs  = (const float*)d_in[3];
    const float* rw1 = (const float*)d_in[4];
    const float* rb1 = (const float*)d_in[5];
    const float* rw2 = (const float*)d_in[6];
    const float* rb2 = (const float*)d_in[7];
    const float* rw3 = (const float*)d_in[8];
    const float* rb3 = (const float*)d_in[9];
    float* out  = (float*)d_out;
    float* mask = out + (size_t)BATCH * DIM;

    // ws layout: Wb (8MB) | hb0 (32MB) | hb1 (32MB) | routing (32KB) | mm | flags
    char* ws = (char*)d_ws;
    unsigned short* Wb  = (unsigned short*)ws;
    unsigned short* hb0 = (unsigned short*)(ws + (size_t)8  * 1024 * 1024);
    unsigned short* hb1 = (unsigned short*)(ws + (size_t)40 * 1024 * 1024);
    int*   routing = (int*)  (ws + (size_t)72 * 1024 * 1024);
    float* mm      = (float*)(ws + (size_t)72 * 1024 * 1024 + 64 * 1024);
    int*   flags   = (int*)  (ws + (size_t)72 * 1024 * 1024 + 64 * 1024 + 16);

    minmax_k<<<1, 1024, 0, stream>>>(unc, mm, flags, BATCH);
    route_k<<<BATCH / 256, 256, 0, stream>>>(unc, mm, rw1, rb1, rw2, rb2, rw3, rb3,
                                             routing, mask, flags, BATCH);
    convx_k<<<(BATCH * DIM / 8 + 255) / 256, 256, 0, stream>>>(x, hb0, BATCH * DIM / 8);

    // chain: hb0(x) -W0-> hb1(lvl0) -W1-> hb0(lvl1) -W2-> hb1 -W3-> (lvl2, no Ob)
    const unsigned short* ins[4]  = {hb0, hb1, hb0, hb1};
    unsigned short*       outs[4] = {hb1, hb0, hb1, hb0};
    const int matches[4]   = {0, 1, -1, 2};
    const int store_ob[4]  = {1, 1, 1, 0};
    const int need_lvl[4]  = {0, 1, 2, 2};
    for (int l = 0; l < 4; ++l) {
        convw_k<<<dim3(64, 64), dim3(32, 8), 0, stream>>>(Ws + (size_t)l * DIM * DIM, Wb,
                                                          flags, need_lvl[l]);
        gemm_k<<<256, 512, 0, stream>>>(ins[l], Wb, outs[l], bs + (size_t)l * DIM,
                                        routing, out, matches[l], store_ob[l], need_lvl[l]);
    }
}

// Round 9
// 475.149 us; speedup vs baseline: 1.4411x; 1.0454x over previous
//
#include <hip/hip_runtime.h>
#include <hip/hip_bf16.h>

#define BATCH 8192
#define DIM   2048

typedef __attribute__((ext_vector_type(8))) short  bf16x8;
typedef __attribute__((ext_vector_type(4))) float  f32x4;

__device__ __forceinline__ unsigned short f2bf(float f) {
    __hip_bfloat16 h = __float2bfloat16(f);
    return *reinterpret_cast<unsigned short*>(&h);
}

// jax.nn.gelu approximate=True: 0.5x(1+tanh(y)) == x*sigmoid(2y), y=c0(x+0.044715x^3)
// sigmoid via hardware v_exp_f32/v_rcp_f32 (~5 instrs vs ~25 for library tanhf).
__device__ __forceinline__ float gelu_f(float x) {
    float z = -1.5957691216057308f * (x + 0.044715f * x * x * x);  // -2*c0*(...)
    return x / (1.0f + __expf(z));
}

__device__ __forceinline__ void gload_lds16(const void* g, void* lds) {
    __builtin_amdgcn_global_load_lds(
        (const __attribute__((address_space(1))) unsigned int*)g,
        (__attribute__((address_space(3))) unsigned int*)lds,
        16, 0, 0);
}

// ---------------- routing ----------------
__global__ void minmax_k(const float* __restrict__ u, float* __restrict__ mm,
                         int* __restrict__ flags, int n) {
    __shared__ float smn[1024], smx[1024];
    int t = threadIdx.x;
    if (t < 2) flags[t] = 0;
    const float4* p = reinterpret_cast<const float4*>(u);
    float4 a = p[2 * t], b = p[2 * t + 1];
    float mn = fminf(fminf(fminf(a.x, a.y), fminf(a.z, a.w)),
                     fminf(fminf(b.x, b.y), fminf(b.z, b.w)));
    float mx = fmaxf(fmaxf(fmaxf(a.x, a.y), fmaxf(a.z, a.w)),
                     fmaxf(fmaxf(b.x, b.y), fmaxf(b.z, b.w)));
    smn[t] = mn; smx[t] = mx;
    __syncthreads();
    for (int s = 512; s > 0; s >>= 1) {
        if (t < s) {
            smn[t] = fminf(smn[t], smn[t + s]);
            smx[t] = fmaxf(smx[t], smx[t + s]);
        }
        __syncthreads();
    }
    if (t == 0) { mm[0] = smn[0]; mm[1] = smx[0]; }
}

// Router weights staged in LDS (fixes the 165us serial-s_load pathology, r2).
__global__ void route_k(const float* __restrict__ unc, const float* __restrict__ mm,
                        const float* __restrict__ rw1, const float* __restrict__ rb1,
                        const float* __restrict__ rw2, const float* __restrict__ rb2,
                        const float* __restrict__ rw3, const float* __restrict__ rb3,
                        int* __restrict__ routing, float* __restrict__ mask_out,
                        int* __restrict__ flags, int n) {
    __shared__ float s_w1[32], s_b1[32], s_w2[512], s_b2[16], s_w3[48], s_b3[3];
    const int t = threadIdx.x;
    if (t < 32) { s_w1[t] = rw1[t]; s_b1[t] = rb1[t]; }
#pragma unroll
    for (int i2 = 0; i2 < 2; ++i2) s_w2[i2 * 256 + t] = rw2[i2 * 256 + t];
    if (t < 16) s_b2[t] = rb2[t];
    if (t < 48) s_w3[t] = rw3[t];
    if (t < 3)  s_b3[t] = rb3[t];
    __syncthreads();

    int i = blockIdx.x * 256 + t;
    float u = (unc[i] - mm[0]) / (mm[1] - mm[0] + 1e-8f);
    float h1[32];
#pragma unroll
    for (int j = 0; j < 32; ++j) h1[j] = fmaxf(u * s_w1[j] + s_b1[j], 0.0f);
    float h2[16];
#pragma unroll
    for (int j = 0; j < 16; ++j) {
        float s = s_b2[j];
#pragma unroll
        for (int k = 0; k < 32; ++k) s += h1[k] * s_w2[k * 16 + j];
        h2[j] = fmaxf(s, 0.0f);
    }
    float lg[3];
#pragma unroll
    for (int j = 0; j < 3; ++j) {
        float s = s_b3[j];
#pragma unroll
        for (int k = 0; k < 16; ++k) s += h2[k] * s_w3[k * 3 + j];
        lg[j] = s;
    }
    // argmax(softmax) == argmax(logits); strict '>' = first-index ties (jnp.argmax)
    int idx = 0; float best = lg[0];
    if (lg[1] > best) { best = lg[1]; idx = 1; }
    if (lg[2] > best) { best = lg[2]; idx = 2; }
    routing[i] = idx;
    mask_out[i] = (float)idx;

    unsigned long long b1 = __ballot(idx >= 1);
    unsigned long long b2 = __ballot(idx >= 2);
    if ((t & 63) == 0) {
        if (b1) atomicOr(&flags[0], 1);
        if (b2) atomicOr(&flags[1], 1);
    }
}

// ---------------- conversions ----------------
__global__ void convx_k(const float* __restrict__ in, unsigned short* __restrict__ out, int n8) {
    int i = blockIdx.x * 256 + threadIdx.x;
    if (i >= n8) return;
    const float4* p = reinterpret_cast<const float4*>(in) + (size_t)2 * i;
    float4 a = p[0], b = p[1];
    bf16x8 o;
    o[0] = (short)f2bf(a.x); o[1] = (short)f2bf(a.y);
    o[2] = (short)f2bf(a.z); o[3] = (short)f2bf(a.w);
    o[4] = (short)f2bf(b.x); o[5] = (short)f2bf(b.y);
    o[6] = (short)f2bf(b.z); o[7] = (short)f2bf(b.w);
    *(reinterpret_cast<bf16x8*>(out) + i) = o;
}

// W [K][N] f32 -> Wt [N][K] bf16, 64x64 tile. Full-line IO: 256B coalesced loads,
// bf16x8 packed 128B-contiguous row stores (old version's 2B stores caused
// half-line write-allocate RMW). LDS reads 2-way conflict max (free, m136).
__global__ void convw_k(const float* __restrict__ W, unsigned short* __restrict__ Wt,
                        const int* __restrict__ flags, int need_lvl) {
    if (need_lvl > 0 && flags[need_lvl - 1] == 0) return;
    __shared__ float lds[64 * 65];
    const int t  = threadIdx.x;          // 256
    const int n0 = blockIdx.x * 64, k0 = blockIdx.y * 64;
    const int c4 = t & 15;               // float4 col
#pragma unroll
    for (int i = 0; i < 4; ++i) {
        int r = (t >> 4) + 16 * i;       // k row 0..63
        float4 v = *(const float4*)(W + (size_t)(k0 + r) * DIM + n0 + c4 * 4);
        lds[r * 65 + c4 * 4 + 0] = v.x;
        lds[r * 65 + c4 * 4 + 1] = v.y;
        lds[r * 65 + c4 * 4 + 2] = v.z;
        lds[r * 65 + c4 * 4 + 3] = v.w;
    }
    __syncthreads();
#pragma unroll
    for (int i = 0; i < 2; ++i) {
        int c2 = t + 256 * i;            // 0..511
        int n  = c2 >> 3;                // out row 0..63
        int kc = c2 & 7;                 // 8-elem k chunk
        bf16x8 o;
#pragma unroll
        for (int j = 0; j < 8; ++j) o[j] = (short)f2bf(lds[(kc * 8 + j) * 65 + n]);
        *(bf16x8*)(Wt + (size_t)(n0 + n) * DIM + k0 + kc * 8) = o;
    }
}

// ---------------- 256x256 8-phase GEMM, counted-vmcnt pipeline (T2+T3+T4+T5) ----
// C[m][n] = gelu(sum_k A[m][k] * Bt[n][k] + bias[n])
// BM=BN=256, BK=64, 512 thr = 8 waves (2M x 4N). LDS 128KiB = 2 dbuf x (A32K|B32K).
// Phases P0..P3 with counted vmcnt (6,6,-,4), never 0 mid-loop (r8: 173->86us).
// New this round: explicit lgkmcnt(0)+sched_barrier(0) before each MFMA cluster
// (m201 fidelity) and exp-based gelu (epilogue VALU cut).
__launch_bounds__(512, 2)
__global__ void gemm_k(const unsigned short* __restrict__ A,
                       const unsigned short* __restrict__ Bt,
                       unsigned short* __restrict__ Ob,   // [M][N] bf16 scratch out
                       const float* __restrict__ bias,    // [N]
                       const int* __restrict__ routing,
                       float* __restrict__ Of,            // [M][N] f32 final out
                       int match, int store_ob, int need_lvl) {
    constexpr int N = DIM, K = DIM;
    constexpr int NT = K / 64;            // 32 K-tiles
    __shared__ char smem[131072];
    __shared__ int s_need;

    const int tid = threadIdx.x;
    // XCD-contiguous remap: 256 wgs, 8 XCDs -> XCD x owns wg [x*32, x*32+32)
    const int wg  = (blockIdx.x & 7) * 32 + (blockIdx.x >> 3);
    const int bm  = wg >> 3;              // 32 M-tiles
    const int bn  = wg & 7;               // 8 N-tiles
    const int m0  = bm * 256, n0 = bn * 256;

    if (need_lvl > 0) {
        if (tid == 0) s_need = 0;
        __syncthreads();
        if (tid < 256 && routing[m0 + tid] >= need_lvl) atomicOr(&s_need, 1);
        __syncthreads();
        if (s_need == 0) return;
    }

    const int wave = tid >> 6, lane = tid & 63;
    const int wm = wave >> 2, wn = wave & 3;      // 2M x 4N wave grid

    // ---- staging (linear LDS dest, inverse-swizzled global src) ----
    const int srow = tid >> 3;                              // 0..63
    const int sw8  = ((tid & 7) ^ (srow & 7)) << 3;         // inv-swizzled elem col
    const unsigned short* gA0 = A  + (size_t)(m0 + srow) * K + sw8;
    const unsigned short* gB0 = Bt + (size_t)(n0 + srow) * K + sw8;
    const int ldsw = wave * 1024;
    auto STAGE = [&](const unsigned short* gb, int koff, int lo) {
        gload_lds16(gb + koff,                  smem + lo + ldsw);
        gload_lds16(gb + (size_t)64 * K + koff, smem + lo + 8192 + ldsw);
    };
    const unsigned short* gA1 = gA0 + (size_t)128 * K;
    const unsigned short* gB1 = gB0 + (size_t)128 * K;

    f32x4 acc[8][4];
#pragma unroll
    for (int i = 0; i < 8; ++i)
#pragma unroll
        for (int j = 0; j < 4; ++j)
            acc[i][j] = (f32x4){0.f, 0.f, 0.f, 0.f};

    const int lrow = lane & 15;
    const int ck0 = (((lane >> 4)    ) ^ (lane & 7)) << 4;   // swizzled 16B chunk, ks=0
    const int ck1 = (((lane >> 4) + 4) ^ (lane & 7)) << 4;   // ks=1

    // prologue: stage tile 0 (order A0,B0,B1,A1), wait A0+B0, raw barrier
    STAGE(gA0, 0, 0);
    STAGE(gB0, 0, 32768);
    STAGE(gB1, 0, 49152);
    STAGE(gA1, 0, 16384);
    asm volatile("s_waitcnt vmcnt(4)" ::: "memory");
    __builtin_amdgcn_s_barrier();

    for (int t = 0; t < NT; ++t) {
        const int bsel = (t & 1) << 16;
        const char* buf = smem + bsel;
        const int nb   = bsel ^ 65536;
        const int ko   = (t + 1) << 6;    // next tile's k elem offset
        const bool pre = (t + 1 < NT);
        bf16x8 aF[4][2], bL[2][2], bH[2][2];

        // ---- P0: read A-low + B-low; stage A0,B0(t+1); vmcnt(6)
#pragma unroll
        for (int f = 0; f < 4; ++f) {
            int ro = (f * 32 + wm * 16 + lrow) * 128;
            aF[f][0] = *(const bf16x8*)(buf + ro + ck0);
            aF[f][1] = *(const bf16x8*)(buf + ro + ck1);
        }
#pragma unroll
        for (int g = 0; g < 2; ++g) {
            int ro = 32768 + (g * 64 + wn * 16 + lrow) * 128;
            bL[g][0] = *(const bf16x8*)(buf + ro + ck0);
            bL[g][1] = *(const bf16x8*)(buf + ro + ck1);
        }
        if (pre) {
            STAGE(gA0, ko, nb);
            STAGE(gB0, ko, nb + 32768);
            asm volatile("s_waitcnt vmcnt(6)" ::: "memory");
        } else {
            asm volatile("s_waitcnt vmcnt(2)" ::: "memory");
        }
        __builtin_amdgcn_s_barrier();
        asm volatile("s_waitcnt lgkmcnt(0)" ::: "memory");
        __builtin_amdgcn_sched_barrier(0);
        __builtin_amdgcn_s_setprio(1);
#pragma unroll
        for (int ks = 0; ks < 2; ++ks)
#pragma unroll
            for (int f = 0; f < 4; ++f)
#pragma unroll
                for (int g = 0; g < 2; ++g)
                    acc[f][g] = __builtin_amdgcn_mfma_f32_16x16x32_bf16(
                        aF[f][ks], bL[g][ks], acc[f][g], 0, 0, 0);
        __builtin_amdgcn_s_setprio(0);
        __builtin_amdgcn_s_barrier();

        // ---- P1: read B-high; stage B1(t+1); vmcnt(6)
#pragma unroll
        for (int g = 0; g < 2; ++g) {
            int ro = 32768 + (128 + g * 64 + wn * 16 + lrow) * 128;
            bH[g][0] = *(const bf16x8*)(buf + ro + ck0);
            bH[g][1] = *(const bf16x8*)(buf + ro + ck1);
        }
        if (pre) {
            STAGE(gB1, ko, nb + 49152);
            asm volatile("s_waitcnt vmcnt(6)" ::: "memory");
        } else {
            asm volatile("s_waitcnt vmcnt(0)" ::: "memory");
        }
        __builtin_amdgcn_s_barrier();
        asm volatile("s_waitcnt lgkmcnt(0)" ::: "memory");
        __builtin_amdgcn_sched_barrier(0);
        __builtin_amdgcn_s_setprio(1);
#pragma unroll
        for (int ks = 0; ks < 2; ++ks)
#pragma unroll
            for (int f = 0; f < 4; ++f)
#pragma unroll
                for (int g = 0; g < 2; ++g)
                    acc[f][2 + g] = __builtin_amdgcn_mfma_f32_16x16x32_bf16(
                        aF[f][ks], bH[g][ks], acc[f][2 + g], 0, 0, 0);
        __builtin_amdgcn_s_setprio(0);
        __builtin_amdgcn_s_barrier();

        // ---- P2: read A-high (overwrite aF); stage A1(t+1); no wait
#pragma unroll
        for (int f = 0; f < 4; ++f) {
            int ro = (128 + f * 32 + wm * 16 + lrow) * 128;
            aF[f][0] = *(const bf16x8*)(buf + ro + ck0);
            aF[f][1] = *(const bf16x8*)(buf + ro + ck1);
        }
        if (pre) STAGE(gA1, ko, nb + 16384);
        __builtin_amdgcn_s_barrier();
        asm volatile("s_waitcnt lgkmcnt(0)" ::: "memory");
        __builtin_amdgcn_sched_barrier(0);
        __builtin_amdgcn_s_setprio(1);
#pragma unroll
        for (int ks = 0; ks < 2; ++ks)
#pragma unroll
            for (int f = 0; f < 4; ++f)
#pragma unroll
                for (int g = 0; g < 2; ++g)
                    acc[4 + f][2 + g] = __builtin_amdgcn_mfma_f32_16x16x32_bf16(
                        aF[f][ks], bH[g][ks], acc[4 + f][2 + g], 0, 0, 0);
        __builtin_amdgcn_s_setprio(0);
        __builtin_amdgcn_s_barrier();

        // ---- P3: pure MFMA; tile-boundary counted wait vmcnt(4)
        if (pre) asm volatile("s_waitcnt vmcnt(4)" ::: "memory");
        __builtin_amdgcn_s_barrier();
        __builtin_amdgcn_s_setprio(1);
#pragma unroll
        for (int ks = 0; ks < 2; ++ks)
#pragma unroll
            for (int f = 0; f < 4; ++f)
#pragma unroll
                for (int g = 0; g < 2; ++g)
                    acc[4 + f][g] = __builtin_amdgcn_mfma_f32_16x16x32_bf16(
                        aF[f][ks], bL[g][ks], acc[4 + f][g], 0, 0, 0);
        __builtin_amdgcn_s_setprio(0);
        __builtin_amdgcn_s_barrier();
    }

    // ---- epilogue: C col = lane&15, row = (lane>>4)*4 + rr; direct stores ----
    // frag->coord: row = m0 + (mf&3)*32 + (mf>>2)*128 + wm*16 + rsub + rr
    //              col = n0 + nf*64 + wn*16 + lrow
    const int c0 = n0 + wn * 16;
    float bcol[4];
#pragma unroll
    for (int nf = 0; nf < 4; ++nf) bcol[nf] = bias[c0 + nf * 64 + lrow];
    const int rsub = (lane >> 4) * 4;

#pragma unroll
    for (int mf = 0; mf < 8; ++mf) {
        const int rbase = m0 + (mf & 3) * 32 + (mf >> 2) * 128 + wm * 16 + rsub;
#pragma unroll
        for (int rr = 0; rr < 4; ++rr) {
            int row = rbase + rr;
            int rt  = routing[row];
            size_t base = (size_t)row * N + c0 + lrow;
#pragma unroll
            for (int nf = 0; nf < 4; ++nf) {
                float v = gelu_f(acc[mf][nf][rr] + bcol[nf]);
                if (store_ob)    Ob[base + nf * 64] = f2bf(v);
                if (rt == match) Of[base + nf * 64] = v;
            }
        }
    }
}

extern "C" void kernel_launch(void* const* d_in, const int* in_sizes, int n_in,
                              void* d_out, int out_size, void* d_ws, size_t ws_size,
                              hipStream_t stream) {
    const float* x   = (const float*)d_in[0];
    const float* unc = (const float*)d_in[1];
    const float* Ws  = (const float*)d_in[2];
    const float* bs  = (const float*)d_in[3];
    const float* rw1 = (const float*)d_in[4];
    const float* rb1 = (const float*)d_in[5];
    const float* rw2 = (const float*)d_in[6];
    const float* rb2 = (const float*)d_in[7];
    const float* rw3 = (const float*)d_in[8];
    const float* rb3 = (const float*)d_in[9];
    float* out  = (float*)d_out;
    float* mask = out + (size_t)BATCH * DIM;

    // ws layout: Wb (8MB) | hb0 (32MB) | hb1 (32MB) | routing (32KB) | mm | flags
    char* ws = (char*)d_ws;
    unsigned short* Wb  = (unsigned short*)ws;
    unsigned short* hb0 = (unsigned short*)(ws + (size_t)8  * 1024 * 1024);
    unsigned short* hb1 = (unsigned short*)(ws + (size_t)40 * 1024 * 1024);
    int*   routing = (int*)  (ws + (size_t)72 * 1024 * 1024);
    float* mm      = (float*)(ws + (size_t)72 * 1024 * 1024 + 64 * 1024);
    int*   flags   = (int*)  (ws + (size_t)72 * 1024 * 1024 + 64 * 1024 + 16);

    minmax_k<<<1, 1024, 0, stream>>>(unc, mm, flags, BATCH);
    route_k<<<BATCH / 256, 256, 0, stream>>>(unc, mm, rw1, rb1, rw2, rb2, rw3, rb3,
                                             routing, mask, flags, BATCH);
    convx_k<<<(BATCH * DIM / 8 + 255) / 256, 256, 0, stream>>>(x, hb0, BATCH * DIM / 8);

    // chain: hb0(x) -W0-> hb1(lvl0) -W1-> hb0(lvl1) -W2-> hb1 -W3-> (lvl2, no Ob)
    const unsigned short* ins[4]  = {hb0, hb1, hb0, hb1};
    unsigned short*       outs[4] = {hb1, hb0, hb1, hb0};
    const int matches[4]   = {0, 1, -1, 2};
    const int store_ob[4]  = {1, 1, 1, 0};
    const int need_lvl[4]  = {0, 1, 2, 2};
    for (int l = 0; l < 4; ++l) {
        convw_k<<<dim3(32, 32), 256, 0, stream>>>(Ws + (size_t)l * DIM * DIM, Wb,
                                                  flags, need_lvl[l]);
        gemm_k<<<256, 512, 0, stream>>>(ins[l], Wb, outs[l], bs + (size_t)l * DIM,
                                        routing, out, matches[l], store_ob[l], need_lvl[l]);
    }
}